// Round 1
// baseline (495.811 us; speedup 1.0000x reference)
//
#include <hip/hip_runtime.h>
#include <math.h>

typedef __attribute__((ext_vector_type(8))) short bf16x8;
typedef __attribute__((ext_vector_type(4))) float f32x4;

#define HEADS 32
#define SEQT  8192
#define DIM   128
#define NQ    16
#define BPH   16            // blocks per head
#define WTOK  128           // tokens per wave
#define TILE  32
#define NPART (BPH * 4)     // partials per head (one per wave)
#define PSTR  132           // floats per q-row in partial: [m,l,pad,pad, acc(128)]
#define QPAD  136           // bf16 row stride (128 + 8 pad: keeps 16B align, breaks bank conflicts)
#define QSCALE 0.08838834764831845f  // 1/sqrt(128)

#define DPP_ROW_SHL(N) (0x100 | (N))
#define DPP_ROW_SHR(N) (0x110 | (N))

template <int CTRL>
__device__ __forceinline__ float dppmov(float old, float v) {
  return __int_as_float(__builtin_amdgcn_update_dpp(
      __float_as_int(old), __float_as_int(v), CTRL, 0xF, 0xF, false));
}
__device__ __forceinline__ float rdlane(float v, int l) {
  return __int_as_float(__builtin_amdgcn_readlane(__float_as_int(v), l));
}
__device__ __forceinline__ unsigned short f2bf(float f) {
  unsigned u = __float_as_uint(f);
  u += 0x7FFFu + ((u >> 16) & 1u);  // RNE
  return (unsigned short)(u >> 16);
}
// idx = round(acos(c)*7/pi) via threshold counting (acos monotone decreasing)
__device__ __forceinline__ int idx7(float x, float s) {
  int i = 0;
  i += x <  0.9749279121818236f   * s;
  i += x <  0.7818314824680298f   * s;
  i += x <  0.4338837391175581f   * s;
  i += x <  6.123233995736766e-17f * s;
  i += x < -0.4338837391175581f   * s;
  i += x < -0.7818314824680298f   * s;
  i += x < -0.9749279121818236f   * s;
  return i;
}

// Wave-cooperative polar compress+decompress round-trip for one 128-dim vector.
// Lane holds dims (2*lane, 2*lane+1). Must be called with all 64 lanes active.
__device__ __forceinline__ float2 polar_rt(float x0, float x1, int lane,
                                           const float2* lutA, const float2* lutB) {
  float a = x0 * x0;
  float p = fmaf(x1, x1, a);
  // within-row (16-lane) suffix sum via DPP row_shl (lane i pulls lane i+N)
  float v = p;
  v += dppmov<DPP_ROW_SHL(1)>(0.f, v);
  v += dppmov<DPP_ROW_SHL(2)>(0.f, v);
  v += dppmov<DPP_ROW_SHL(4)>(0.f, v);
  v += dppmov<DPP_ROW_SHL(8)>(0.f, v);
  // cross-row stitch: row totals live at lanes 0,16,32,48
  float R0 = rdlane(v, 0), R1 = rdlane(v, 16), R2 = rdlane(v, 32), R3 = rdlane(v, 48);
  float T2 = R3, T1 = R2 + R3, T0 = R1 + T1;
  int row = lane >> 4;
  float T = (row == 0) ? T0 : ((row == 1) ? T1 : ((row == 2) ? T2 : 0.f));
  float ss0 = v + T;          // suffix sum of squares at dim 2*lane
  float total = R0 + T0;
  float ss1 = ss0 - a;        // suffix at dim 2*lane+1
  float s0 = sqrtf(ss0);
  float s1 = sqrtf(ss1);
  float rad = sqrtf(total);
  float2 sc0, sc1;
  if (lane == 63) {
    // dim 126: 2*pi range, reflected by sign of x127 (=x1 here)
    int ib = 0;
    ib += x0 <  0.9009688679024191f * s0;
    ib += x0 <  0.2225209339563144f * s0;
    ib += x0 < -0.6234898018587336f * s0;
    int i0 = (x1 < 0.f) ? (7 - ib) : ib;
    sc0 = lutB[i0];
    sc1 = make_float2(1.f, 1.f);   // dim 127 has no angle: cos := 1
  } else {
    sc0 = lutA[idx7(x0, s0)];
    sc1 = lutA[idx7(x1, s1)];
  }
  // exclusive prefix product of sin over dims: within-row inclusive via row_shr,
  // shift for exclusive, stitch previous-row full products (lanes 15,31,47)
  float qp = sc0.x * sc1.x;
  float w = qp;
  w *= dppmov<DPP_ROW_SHR(1)>(1.f, w);
  w *= dppmov<DPP_ROW_SHR(2)>(1.f, w);
  w *= dppmov<DPP_ROW_SHR(4)>(1.f, w);
  w *= dppmov<DPP_ROW_SHR(8)>(1.f, w);
  float e = dppmov<DPP_ROW_SHR(1)>(1.f, w);
  float F0 = rdlane(w, 15), F1 = rdlane(w, 31), F2 = rdlane(w, 47);
  float M1 = F0, M2 = F0 * F1, M3 = M2 * F2;
  float M = (row == 0) ? 1.f : ((row == 1) ? M1 : ((row == 2) ? M2 : M3));
  float E = e * M;            // prod of sin over dims < 2*lane
  float rE = rad * E;
  return make_float2(rE * sc0.y, rE * sc0.x * sc1.y);
}

__global__ __launch_bounds__(256, 2)
void attn_partial(const float* __restrict__ Q, const float* __restrict__ K,
                  const float* __restrict__ V, const float* __restrict__ noise,
                  float* __restrict__ part) {
  __shared__ unsigned short Qs[NQ * QPAD];
  __shared__ unsigned short Ks[4][TILE * QPAD];
  __shared__ float Ps[4][TILE * NQ];
  __shared__ float2 lutA[8];
  __shared__ float2 lutB[8];

  const int tid  = threadIdx.x;
  const int lane = tid & 63;
  const int wv   = tid >> 6;
  const int h    = blockIdx.x / BPH;
  const int bh   = blockIdx.x % BPH;

  if (tid < 8) {
    // exact fp32 angles the reference computes: fl(i/7) * fl(pi), fl(i/7) * fl(2pi)
    float fi = (float)tid / 7.0f;
    float ta = fi * 3.14159274101257324f;
    float tb = fi * 6.28318548202514648f;
    lutA[tid] = make_float2(sinf(ta), cosf(ta));
    lutB[tid] = make_float2(sinf(tb), cosf(tb));
  }
  {
    const float* Qh = Q + (size_t)h * NQ * DIM;
    for (int i = tid; i < NQ * DIM; i += 256)
      Qs[(i >> 7) * QPAD + (i & 127)] = f2bf(Qh[i] * QSCALE);
  }
  __syncthreads();

  const int G = lane >> 4, r16 = lane & 15;
  bf16x8 qa[4];  // Q A-frags cached in registers for the whole block
#pragma unroll
  for (int c = 0; c < 4; ++c)
    qa[c] = *(const bf16x8*)&Qs[r16 * QPAD + c * 32 + G * 8];

  float acc[NQ][2];
#pragma unroll
  for (int qq = 0; qq < NQ; ++qq) { acc[qq][0] = 0.f; acc[qq][1] = 0.f; }
  float m_r[4] = {-INFINITY, -INFINITY, -INFINITY, -INFINITY};
  float l_r[4] = {0.f, 0.f, 0.f, 0.f};

  const size_t hoff = (size_t)h * SEQT * DIM;
  const int t0 = (bh * 4 + wv) * WTOK;
  const float2* Kp = (const float2*)(K + hoff + (size_t)t0 * DIM) + lane;
  const float2* Vp = (const float2*)(V + hoff + (size_t)t0 * DIM) + lane;
  const float* nh = noise + (size_t)h * NQ * SEQT + t0 + r16;
  unsigned short* myK = Ks[wv];
  float* myP = Ps[wv];

#pragma unroll 1
  for (int tile = 0; tile < WTOK / TILE; ++tile) {
    // ---- decompress K tile -> LDS (bf16, row-major, padded)
#pragma unroll 2
    for (int tt = 0; tt < TILE; ++tt) {
      float2 xv = Kp[(tile * TILE + tt) * 64];
      float2 kh = polar_rt(xv.x, xv.y, lane, lutA, lutB);
      unsigned pk = (unsigned)f2bf(kh.x) | ((unsigned)f2bf(kh.y) << 16);
      ((unsigned*)&myK[tt * QPAD])[lane] = pk;
    }
    // ---- scores: D[q][t] = (Q/sqrt(d)) . Khat, K=128 chained over 4 MFMAs
    f32x4 d0 = {0.f, 0.f, 0.f, 0.f};
    f32x4 d1 = {0.f, 0.f, 0.f, 0.f};
#pragma unroll
    for (int c = 0; c < 4; ++c) {
      bf16x8 b0 = *(const bf16x8*)&myK[r16 * QPAD + c * 32 + G * 8];
      d0 = __builtin_amdgcn_mfma_f32_16x16x32_bf16(qa[c], b0, d0, 0, 0, 0);
    }
#pragma unroll
    for (int c = 0; c < 4; ++c) {
      bf16x8 b1 = *(const bf16x8*)&myK[(16 + r16) * QPAD + c * 32 + G * 8];
      d1 = __builtin_amdgcn_mfma_f32_16x16x32_bf16(qa[c], b1, d1, 0, 0, 0);
    }
    const float* nt = nh + tile * TILE;
    float s0_[4], s1_[4];
#pragma unroll
    for (int rr = 0; rr < 4; ++rr) {
      int qq = 4 * G + rr;
      s0_[rr] = d0[rr] + nt[(size_t)qq * SEQT];
      s1_[rr] = d1[rr] + nt[(size_t)qq * SEQT + 16];
    }
    // ---- online softmax: quad G owns queries 4G..4G+3 (MFMA C/D layout)
    float al_r[4];
#pragma unroll
    for (int rr = 0; rr < 4; ++rr) {
      float mt = fmaxf(s0_[rr], s1_[rr]);
#pragma unroll
      for (int off = 1; off < 16; off <<= 1)
        mt = fmaxf(mt, __shfl_xor(mt, off, 64));
      float mn = fmaxf(m_r[rr], mt);
      al_r[rr] = __expf(m_r[rr] - mn);
      m_r[rr] = mn;
    }
    float p0[4], p1[4];
#pragma unroll
    for (int rr = 0; rr < 4; ++rr) {
      p0[rr] = __expf(s0_[rr] - m_r[rr]);
      p1[rr] = __expf(s1_[rr] - m_r[rr]);
      float sp = p0[rr] + p1[rr];
#pragma unroll
      for (int off = 1; off < 16; off <<= 1)
        sp += __shfl_xor(sp, off, 64);
      l_r[rr] = l_r[rr] * al_r[rr] + sp;
    }
    // stash p as [t][q] so PV can read 4 broadcast float4s per token
    *(float4*)&myP[r16 * NQ + 4 * G] = make_float4(p0[0], p0[1], p0[2], p0[3]);
    *(float4*)&myP[(16 + r16) * NQ + 4 * G] = make_float4(p1[0], p1[1], p1[2], p1[3]);
    // rescale accumulator (alpha broadcast via readlane from owner quad)
#pragma unroll
    for (int qq = 0; qq < NQ; ++qq) {
      float alq = rdlane(al_r[qq & 3], (qq >> 2) << 4);
      acc[qq][0] *= alq; acc[qq][1] *= alq;
    }
    // ---- PV: decompress V straight into registers, fp32 FMA accumulate
#pragma unroll 2
    for (int tt = 0; tt < TILE; ++tt) {
      float2 xv = Vp[(tile * TILE + tt) * 64];
      float2 vh = polar_rt(xv.x, xv.y, lane, lutA, lutB);
      const float* pv = &myP[tt * NQ];
      float4 pa = ((const float4*)pv)[0];
      float4 pb = ((const float4*)pv)[1];
      float4 pc = ((const float4*)pv)[2];
      float4 pd = ((const float4*)pv)[3];
      float pq[NQ] = {pa.x, pa.y, pa.z, pa.w, pb.x, pb.y, pb.z, pb.w,
                      pc.x, pc.y, pc.z, pc.w, pd.x, pd.y, pd.z, pd.w};
#pragma unroll
      for (int qq = 0; qq < NQ; ++qq) {
        acc[qq][0] = fmaf(pq[qq], vh.x, acc[qq][0]);
        acc[qq][1] = fmaf(pq[qq], vh.y, acc[qq][1]);
      }
    }
  }
  // ---- write partial (m, l, unnormalized acc)
  {
    const int pidx = bh * 4 + wv;
    float* P = part + ((size_t)h * NPART + pidx) * (NQ * PSTR);
    if (r16 == 0) {
#pragma unroll
      for (int rr = 0; rr < 4; ++rr) {
        P[(4 * G + rr) * PSTR + 0] = m_r[rr];
        P[(4 * G + rr) * PSTR + 1] = l_r[rr];
      }
    }
#pragma unroll
    for (int qq = 0; qq < NQ; ++qq)
      *(float2*)&P[qq * PSTR + 4 + 2 * lane] = make_float2(acc[qq][0], acc[qq][1]);
  }
}

__global__ __launch_bounds__(256)
void attn_reduce(const float* __restrict__ part, float* __restrict__ out) {
  __shared__ float wgt[NPART][NQ];
  __shared__ float Ms[NQ];
  __shared__ float Ls[NQ];
  const int tid = threadIdx.x;
  const int h = blockIdx.x;
  const float* P = part + (size_t)h * NPART * NQ * PSTR;
  if (tid < NQ) {
    float M = -INFINITY;
    for (int c = 0; c < NPART; ++c)
      M = fmaxf(M, P[(c * NQ + tid) * PSTR]);
    float L = 0.f;
    for (int c = 0; c < NPART; ++c)
      L += P[(c * NQ + tid) * PSTR + 1] * __expf(P[(c * NQ + tid) * PSTR] - M);
    Ms[tid] = M; Ls[tid] = L;
  }
  __syncthreads();
  for (int i = tid; i < NPART * NQ; i += 256) {
    int c = i >> 4, q = i & 15;
    wgt[c][q] = __expf(P[(c * NQ + q) * PSTR] - Ms[q]);
  }
  __syncthreads();
  const int q = tid >> 4;
  const int d0 = (tid & 15) * 8;
  float o[8] = {0.f, 0.f, 0.f, 0.f, 0.f, 0.f, 0.f, 0.f};
  for (int c = 0; c < NPART; ++c) {
    const float* A = &P[(c * NQ + q) * PSTR + 4 + d0];
    float wq = wgt[c][q];
    float4 a0 = *(const float4*)A;
    float4 a1 = *(const float4*)(A + 4);
    o[0] = fmaf(wq, a0.x, o[0]); o[1] = fmaf(wq, a0.y, o[1]);
    o[2] = fmaf(wq, a0.z, o[2]); o[3] = fmaf(wq, a0.w, o[3]);
    o[4] = fmaf(wq, a1.x, o[4]); o[5] = fmaf(wq, a1.y, o[5]);
    o[6] = fmaf(wq, a1.z, o[6]); o[7] = fmaf(wq, a1.w, o[7]);
  }
  float inv = 1.0f / Ls[q];
  float* O = out + ((size_t)h * NQ + q) * DIM + d0;
  float4 w0 = make_float4(o[0] * inv, o[1] * inv, o[2] * inv, o[3] * inv);
  float4 w1 = make_float4(o[4] * inv, o[5] * inv, o[6] * inv, o[7] * inv);
  *(float4*)O = w0;
  *(float4*)(O + 4) = w1;
}

extern "C" void kernel_launch(void* const* d_in, const int* in_sizes, int n_in,
                              void* d_out, int out_size, void* d_ws, size_t ws_size,
                              hipStream_t stream) {
  (void)in_sizes; (void)n_in; (void)out_size; (void)ws_size;
  const float* Q = (const float*)d_in[0];
  const float* K = (const float*)d_in[1];
  const float* V = (const float*)d_in[2];
  const float* noise = (const float*)d_in[3];
  float* part = (float*)d_ws;  // 32*64*16*132*4 B = 17.3 MB
  attn_partial<<<dim3(HEADS * BPH), dim3(256), 0, stream>>>(Q, K, V, noise, part);
  attn_reduce<<<dim3(HEADS), dim3(256), 0, stream>>>(part, (float*)d_out);
}

// Round 2
// 402.826 us; speedup vs baseline: 1.2308x; 1.2308x over previous
//
#include <hip/hip_runtime.h>
#include <math.h>

typedef __attribute__((ext_vector_type(8))) short bf16x8;
typedef __attribute__((ext_vector_type(4))) float f32x4;

#define HEADS 32
#define SEQT  8192
#define DIM   128
#define NQ    16
#define BPH   64            // blocks per head
#define BTOK  128           // tokens per block
#define WTOK  32            // tokens per wave
#define TILE  16
#define NPART BPH           // one partial per BLOCK (4 waves merged in LDS)
#define PSTR  132           // floats per q-row in partial: [m,l,pad,pad, acc(128)]
#define QPAD  136           // bf16 row stride (16B-aligned rows, 2-way-only bank aliasing)
#define QSCALE 0.08838834764831845f  // 1/sqrt(128)

// LDS layout (bytes). merge buffer overlays Ks (dead by merge time).
#define OFF_QS    0          // 16*136*2      = 4352
#define OFF_PS    4352       // 4*16*16*4     = 4096
#define OFF_LUT   8448       // 16*float2     = 128
#define OFF_ML    8576       // 4*16*float2   = 512
#define OFF_KS    9088       // 4*16*136*2    = 17408
#define OFF_MERGE 9088       // 2*16*128*4    = 16384 (overlay)
#define LDS_BYTES 26496

#define DPP_ROW_SHL(N) (0x100 | (N))
#define DPP_ROW_SHR(N) (0x110 | (N))

template <int CTRL>
__device__ __forceinline__ float dpp0(float v) {  // out-of-range lanes read 0
  return __int_as_float(__builtin_amdgcn_update_dpp(
      0, __float_as_int(v), CTRL, 0xF, 0xF, true));
}
template <int CTRL>
__device__ __forceinline__ float dpp1(float v) {  // out-of-range lanes keep 1.0
  return __int_as_float(__builtin_amdgcn_update_dpp(
      __float_as_int(1.0f), __float_as_int(v), CTRL, 0xF, 0xF, false));
}
__device__ __forceinline__ float rdlane(float v, int l) {
  return __int_as_float(__builtin_amdgcn_readlane(__float_as_int(v), l));
}
__device__ __forceinline__ unsigned short f2bf(float f) {
  unsigned u = __float_as_uint(f);
  u += 0x7FFFu + ((u >> 16) & 1u);  // RNE
  return (unsigned short)(u >> 16);
}
// idx = round(acos(c)*7/pi) via threshold counting on c = x*rsqrt(ss)
__device__ __forceinline__ int idx7c(float c) {
  int i = 0;
  i += c <  0.9749279121818236f;
  i += c <  0.7818314824680298f;
  i += c <  0.4338837391175581f;
  i += c <  6.123233995736766e-17f;
  i += c < -0.4338837391175581f;
  i += c < -0.7818314824680298f;
  i += c < -0.9749279121818236f;
  return i;
}

// Wave-cooperative polar compress+decompress round-trip for one 128-dim vector.
// Lane holds dims (2*lane, 2*lane+1). All 64 lanes must be active.
__device__ __forceinline__ float2 polar_rt(float x0, float x1, int lane,
                                           const float2* lutA, const float2* lutB) {
  float a = x0 * x0;
  float p = fmaf(x1, x1, a);
  // within-row (16-lane) suffix sum via DPP row_shl
  float v = p;
  v += dpp0<DPP_ROW_SHL(1)>(v);
  v += dpp0<DPP_ROW_SHL(2)>(v);
  v += dpp0<DPP_ROW_SHL(4)>(v);
  v += dpp0<DPP_ROW_SHL(8)>(v);
  // cross-row stitch: row totals at lanes 0,16,32,48
  float R0 = rdlane(v, 0), R1 = rdlane(v, 16), R2 = rdlane(v, 32), R3 = rdlane(v, 48);
  float T2 = R3, T1 = R2 + R3, T0 = R1 + T1;
  int row = lane >> 4;
  float T = (row == 0) ? T0 : ((row == 1) ? T1 : ((row == 2) ? T2 : 0.f));
  float ss0 = v + T;          // suffix sum of squares at dim 2*lane
  float total = R0 + T0;
  float ss1 = ss0 - a;        // suffix at dim 2*lane+1
  float c0 = x0 * __builtin_amdgcn_rsqf(ss0);
  float c1 = x1 * __builtin_amdgcn_rsqf(ss1);
  float rad = sqrtf(total);
  // unconditional common path, lane-63 override
  float2 sc0 = lutA[idx7c(c0)];
  float2 sc1 = lutA[idx7c(c1)];
  if (lane == 63) {
    int ib = 0;
    ib += c0 <  0.9009688679024191f;
    ib += c0 <  0.2225209339563144f;
    ib += c0 < -0.6234898018587336f;
    int i0 = (x1 < 0.f) ? (7 - ib) : ib;
    sc0 = lutB[i0];
    sc1 = make_float2(1.f, 1.f);   // dim 127 has no angle
  }
  // exclusive prefix product of sin over dims
  float qp = sc0.x * sc1.x;
  float w = qp;
  w *= dpp1<DPP_ROW_SHR(1)>(w);
  w *= dpp1<DPP_ROW_SHR(2)>(w);
  w *= dpp1<DPP_ROW_SHR(4)>(w);
  w *= dpp1<DPP_ROW_SHR(8)>(w);
  float e = dpp1<DPP_ROW_SHR(1)>(w);
  float F0 = rdlane(w, 15), F1 = rdlane(w, 31), F2 = rdlane(w, 47);
  float M1 = F0, M2 = F0 * F1, M3 = M2 * F2;
  float M = (row == 0) ? 1.f : ((row == 1) ? M1 : ((row == 2) ? M2 : M3));
  float E = e * M;            // prod of sin over dims < 2*lane
  float rE = rad * E;
  return make_float2(rE * sc0.y, rE * sc0.x * sc1.y);
}

__global__ __launch_bounds__(256, 6)
void attn_partial(const float* __restrict__ Q, const float* __restrict__ K,
                  const float* __restrict__ V, const float* __restrict__ noise,
                  float* __restrict__ part) {
  __shared__ __align__(16) char RAW[LDS_BYTES];
  unsigned short* Qs  = (unsigned short*)(RAW + OFF_QS);
  float*          Ps  = (float*)(RAW + OFF_PS);
  float2*         lutA = (float2*)(RAW + OFF_LUT);
  float2*         lutB = lutA + 8;
  float2*         Ml  = (float2*)(RAW + OFF_ML);   // [wave][q]
  unsigned short* Ks  = (unsigned short*)(RAW + OFF_KS);

  const int tid  = threadIdx.x;
  const int lane = tid & 63;
  const int wv   = tid >> 6;
  const int h    = blockIdx.x / BPH;
  const int bh   = blockIdx.x % BPH;

  if (tid < 8) {
    float fi = (float)tid / 7.0f;
    float ta = fi * 3.14159274101257324f;
    float tb = fi * 6.28318548202514648f;
    lutA[tid] = make_float2(sinf(ta), cosf(ta));
    lutB[tid] = make_float2(sinf(tb), cosf(tb));
  }
  {
    const float* Qh = Q + (size_t)h * NQ * DIM;
    for (int i = tid; i < NQ * DIM; i += 256)
      Qs[(i >> 7) * QPAD + (i & 127)] = f2bf(Qh[i] * QSCALE);
  }
  __syncthreads();

  const int G = lane >> 4, r16 = lane & 15;
  bf16x8 qa[4];
#pragma unroll
  for (int c = 0; c < 4; ++c)
    qa[c] = *(const bf16x8*)&Qs[r16 * QPAD + c * 32 + G * 8];

  float acc[NQ][2];
#pragma unroll
  for (int qq = 0; qq < NQ; ++qq) { acc[qq][0] = 0.f; acc[qq][1] = 0.f; }
  float m_r[4] = {-INFINITY, -INFINITY, -INFINITY, -INFINITY};
  float l_r[4] = {0.f, 0.f, 0.f, 0.f};

  const size_t hoff = (size_t)h * SEQT * DIM;
  const int t0 = bh * BTOK + wv * WTOK;
  const float2* Kp = (const float2*)(K + hoff + (size_t)t0 * DIM) + lane;
  const float2* Vp = (const float2*)(V + hoff + (size_t)t0 * DIM) + lane;
  const float* nh = noise + (size_t)h * NQ * SEQT + t0 + r16;
  unsigned short* myK = Ks + wv * TILE * QPAD;
  float* myP = Ps + wv * TILE * NQ;

#pragma unroll 1
  for (int tile = 0; tile < WTOK / TILE; ++tile) {
    // ---- decompress K tile -> LDS (bf16)
#pragma unroll 2
    for (int tt = 0; tt < TILE; ++tt) {
      float2 xv = Kp[(tile * TILE + tt) * 64];
      float2 kh = polar_rt(xv.x, xv.y, lane, lutA, lutB);
      unsigned pk = (unsigned)f2bf(kh.x) | ((unsigned)f2bf(kh.y) << 16);
      ((unsigned*)&myK[tt * QPAD])[lane] = pk;
    }
    // ---- scores via MFMA, K=128 chained
    f32x4 d0 = {0.f, 0.f, 0.f, 0.f};
#pragma unroll
    for (int c = 0; c < 4; ++c) {
      bf16x8 b0 = *(const bf16x8*)&myK[r16 * QPAD + c * 32 + G * 8];
      d0 = __builtin_amdgcn_mfma_f32_16x16x32_bf16(qa[c], b0, d0, 0, 0, 0);
    }
    const float* nt = nh + tile * TILE;
    float s0_[4];
#pragma unroll
    for (int rr = 0; rr < 4; ++rr)
      s0_[rr] = d0[rr] + nt[(size_t)(4 * G + rr) * SEQT];
    // ---- online softmax (quad G owns queries 4G..4G+3)
    float al_r[4];
#pragma unroll
    for (int rr = 0; rr < 4; ++rr) {
      float mt = s0_[rr];
#pragma unroll
      for (int off = 1; off < 16; off <<= 1)
        mt = fmaxf(mt, __shfl_xor(mt, off, 64));
      float mn = fmaxf(m_r[rr], mt);
      al_r[rr] = __expf(m_r[rr] - mn);
      m_r[rr] = mn;
    }
    float p0[4];
#pragma unroll
    for (int rr = 0; rr < 4; ++rr) {
      p0[rr] = __expf(s0_[rr] - m_r[rr]);
      float sp = p0[rr];
#pragma unroll
      for (int off = 1; off < 16; off <<= 1)
        sp += __shfl_xor(sp, off, 64);
      l_r[rr] = l_r[rr] * al_r[rr] + sp;
    }
    *(float4*)&myP[r16 * NQ + 4 * G] = make_float4(p0[0], p0[1], p0[2], p0[3]);
#pragma unroll
    for (int qq = 0; qq < NQ; ++qq) {
      float alq = rdlane(al_r[qq & 3], (qq >> 2) << 4);
      acc[qq][0] *= alq; acc[qq][1] *= alq;
    }
    // ---- PV: decompress V straight into registers, fp32 FMA
#pragma unroll 2
    for (int tt = 0; tt < TILE; ++tt) {
      float2 xv = Vp[(tile * TILE + tt) * 64];
      float2 vh = polar_rt(xv.x, xv.y, lane, lutA, lutB);
      const float* pv = &myP[tt * NQ];
      float4 pa = ((const float4*)pv)[0];
      float4 pb = ((const float4*)pv)[1];
      float4 pc = ((const float4*)pv)[2];
      float4 pd = ((const float4*)pv)[3];
      float pq[NQ] = {pa.x, pa.y, pa.z, pa.w, pb.x, pb.y, pb.z, pb.w,
                      pc.x, pc.y, pc.z, pc.w, pd.x, pd.y, pd.z, pd.w};
#pragma unroll
      for (int qq = 0; qq < NQ; ++qq) {
        acc[qq][0] = fmaf(pq[qq], vh.x, acc[qq][0]);
        acc[qq][1] = fmaf(pq[qq], vh.y, acc[qq][1]);
      }
    }
  }

  // ---- block-level merge of the 4 wave states (online-softmax combine)
  if (r16 == 0) {
#pragma unroll
    for (int rr = 0; rr < 4; ++rr)
      Ml[wv * NQ + 4 * G + rr] = make_float2(m_r[rr], l_r[rr]);
  }
  __syncthreads();   // also fences last Ks use before merge-buffer overlay
#pragma unroll
  for (int qq = 0; qq < NQ; ++qq) {
    float2 e0 = Ml[0 * NQ + qq], e1 = Ml[1 * NQ + qq];
    float2 e2 = Ml[2 * NQ + qq], e3 = Ml[3 * NQ + qq];
    float Mq = fmaxf(fmaxf(e0.x, e1.x), fmaxf(e2.x, e3.x));
    float own = (wv == 0) ? e0.x : ((wv == 1) ? e1.x : ((wv == 2) ? e2.x : e3.x));
    float al = __expf(own - Mq);
    acc[qq][0] *= al; acc[qq][1] *= al;
  }
  float* buf = (float*)(RAW + OFF_MERGE);
  if (wv >= 2) {
#pragma unroll
    for (int qq = 0; qq < NQ; ++qq)
      *(float2*)&buf[(wv - 2) * 2048 + qq * 128 + 2 * lane] =
          make_float2(acc[qq][0], acc[qq][1]);
  }
  __syncthreads();
  if (wv < 2) {
#pragma unroll
    for (int qq = 0; qq < NQ; ++qq) {
      float2 t = *(const float2*)&buf[wv * 2048 + qq * 128 + 2 * lane];
      acc[qq][0] += t.x; acc[qq][1] += t.y;
    }
  }
  __syncthreads();
  if (wv == 1) {
#pragma unroll
    for (int qq = 0; qq < NQ; ++qq)
      *(float2*)&buf[qq * 128 + 2 * lane] = make_float2(acc[qq][0], acc[qq][1]);
  }
  __syncthreads();
  if (wv == 0) {
    float* P = part + ((size_t)h * NPART + bh) * (NQ * PSTR);
#pragma unroll
    for (int qq = 0; qq < NQ; ++qq) {
      float2 t = *(const float2*)&buf[qq * 128 + 2 * lane];
      *(float2*)&P[qq * PSTR + 4 + 2 * lane] =
          make_float2(acc[qq][0] + t.x, acc[qq][1] + t.y);
      // header (uniform across lanes; lane 0 stores)
      float2 e0 = Ml[0 * NQ + qq], e1 = Ml[1 * NQ + qq];
      float2 e2 = Ml[2 * NQ + qq], e3 = Ml[3 * NQ + qq];
      float Mq = fmaxf(fmaxf(e0.x, e1.x), fmaxf(e2.x, e3.x));
      float Lq = e0.y * __expf(e0.x - Mq) + e1.y * __expf(e1.x - Mq) +
                 e2.y * __expf(e2.x - Mq) + e3.y * __expf(e3.x - Mq);
      if (lane == 0) *(float2*)&P[qq * PSTR] = make_float2(Mq, Lq);
    }
  }
}

__global__ __launch_bounds__(128)
void attn_reduce(const float* __restrict__ part, float* __restrict__ out) {
  __shared__ float wgt[NPART];
  __shared__ float Lsh;
  const int tid = threadIdx.x;
  const int h = blockIdx.x >> 4;
  const int q = blockIdx.x & 15;
  const float* P = part + (size_t)h * NPART * NQ * PSTR;
  if (tid < NPART) {
    float2 ml = *(const float2*)&P[((size_t)tid * NQ + q) * PSTR];
    float M = ml.x;
#pragma unroll
    for (int off = 1; off < 64; off <<= 1)
      M = fmaxf(M, __shfl_xor(M, off, 64));
    float w = __expf(ml.x - M);
    wgt[tid] = w;
    float L = ml.y * w;
#pragma unroll
    for (int off = 1; off < 64; off <<= 1)
      L += __shfl_xor(L, off, 64);
    if (tid == 0) Lsh = L;
  }
  __syncthreads();
  const float* A = P + (size_t)q * PSTR + 4 + tid;
  float o = 0.f;
#pragma unroll 8
  for (int c = 0; c < NPART; ++c)
    o = fmaf(wgt[c], A[(size_t)c * NQ * PSTR], o);
  out[((size_t)h * NQ + q) * DIM + tid] = o * (1.0f / Lsh);
}

extern "C" void kernel_launch(void* const* d_in, const int* in_sizes, int n_in,
                              void* d_out, int out_size, void* d_ws, size_t ws_size,
                              hipStream_t stream) {
  (void)in_sizes; (void)n_in; (void)out_size; (void)ws_size;
  const float* Q = (const float*)d_in[0];
  const float* K = (const float*)d_in[1];
  const float* V = (const float*)d_in[2];
  const float* noise = (const float*)d_in[3];
  float* part = (float*)d_ws;  // 32*64*16*132*4 B = 17.3 MB
  attn_partial<<<dim3(HEADS * BPH), dim3(256), 0, stream>>>(Q, K, V, noise, part);
  attn_reduce<<<dim3(HEADS * NQ), dim3(128), 0, stream>>>(part, (float*)d_out);
}

// Round 3
// 369.228 us; speedup vs baseline: 1.3428x; 1.0910x over previous
//
#include <hip/hip_runtime.h>
#include <math.h>

typedef __attribute__((ext_vector_type(8))) short bf16x8;
typedef __attribute__((ext_vector_type(4))) float f32x4;
typedef __attribute__((ext_vector_type(2))) float f32x2;

#define HEADS 32
#define SEQT  8192
#define DIM   128
#define NQ    16
#define BPH   64            // blocks per head
#define BTOK  128           // tokens per block
#define WTOK  32            // tokens per wave
#define TILE  16
#define NPART BPH           // one partial per BLOCK (4 waves merged in LDS)
#define PSTR  132           // floats per q-row in partial: [m,l,pad,pad, acc(128)]
#define QPAD  136           // bf16 row stride (16B-aligned rows, 2-way-only bank aliasing)
#define QSCALE 0.08838834764831845f  // 1/sqrt(128)

// LDS layout (bytes). merge buffer overlays Ks (dead by merge time).
#define OFF_QS    0          // 16*136*2      = 4352
#define OFF_PS    4352       // 4*16*16*4     = 4096
#define OFF_LUT   8448       // 16*float2     = 128
#define OFF_ML    8576       // 4*16*float2   = 512
#define OFF_KS    9088       // 4*16*136*2    = 17408
#define OFF_MERGE 9088       // 2*16*128*4    = 16384 (overlay)
#define LDS_BYTES 26496

#define DPP_ROW_SHL(N) (0x100 | (N))
#define DPP_ROW_SHR(N) (0x110 | (N))
#define DPP_QP_XOR1   0xB1   // quad_perm(1,0,3,2)
#define DPP_QP_XOR2   0x4E   // quad_perm(2,3,0,1)
#define DPP_HALF_MIRR 0x141  // i ^ 7 within row
#define DPP_MIRR      0x140  // i ^ 15 within row

template <int CTRL>
__device__ __forceinline__ float dpp0(float v) {  // out-of-range lanes read 0
  return __int_as_float(__builtin_amdgcn_update_dpp(
      0, __float_as_int(v), CTRL, 0xF, 0xF, true));
}
template <int CTRL>
__device__ __forceinline__ float dpp1(float v) {  // out-of-range lanes keep 1.0
  return __int_as_float(__builtin_amdgcn_update_dpp(
      __float_as_int(1.0f), __float_as_int(v), CTRL, 0xF, 0xF, false));
}
// butterfly reductions over each 16-lane row — pure VALU (no ds_bpermute)
__device__ __forceinline__ float rmax16(float v) {
  v = fmaxf(v, dpp0<DPP_QP_XOR1>(v));
  v = fmaxf(v, dpp0<DPP_QP_XOR2>(v));
  v = fmaxf(v, dpp0<DPP_HALF_MIRR>(v));  // ≡ xor4 once quads uniform
  v = fmaxf(v, dpp0<DPP_MIRR>(v));       // ≡ xor8
  return v;
}
__device__ __forceinline__ float rsum16(float v) {
  v += dpp0<DPP_QP_XOR1>(v);
  v += dpp0<DPP_QP_XOR2>(v);
  v += dpp0<DPP_HALF_MIRR>(v);
  v += dpp0<DPP_MIRR>(v);
  return v;
}
__device__ __forceinline__ float rdlane(float v, int l) {
  return __int_as_float(__builtin_amdgcn_readlane(__float_as_int(v), l));
}
__device__ __forceinline__ unsigned short f2bf(float f) {
  unsigned u = __float_as_uint(f);
  u += 0x7FFFu + ((u >> 16) & 1u);  // RNE
  return (unsigned short)(u >> 16);
}
// idx = round(acos(c)*7/pi) via threshold counting on c = x*rsqrt(ss)
__device__ __forceinline__ int idx7c(float c) {
  int i = 0;
  i += c <  0.9749279121818236f;
  i += c <  0.7818314824680298f;
  i += c <  0.4338837391175581f;
  i += c <  6.123233995736766e-17f;
  i += c < -0.4338837391175581f;
  i += c < -0.7818314824680298f;
  i += c < -0.9749279121818236f;
  return i;
}

// Wave-cooperative polar compress+decompress round-trip for one 128-dim vector.
// Lane holds dims (2*lane, 2*lane+1). All 64 lanes must be active.
__device__ __forceinline__ float2 polar_rt(float x0, float x1, int lane,
                                           const float2* lutA, const float2* lutB) {
  float a = x0 * x0;
  float p = fmaf(x1, x1, a);
  // within-row (16-lane) suffix sum via DPP row_shl
  float v = p;
  v += dpp0<DPP_ROW_SHL(1)>(v);
  v += dpp0<DPP_ROW_SHL(2)>(v);
  v += dpp0<DPP_ROW_SHL(4)>(v);
  v += dpp0<DPP_ROW_SHL(8)>(v);
  // cross-row stitch: row totals at lanes 0,16,32,48
  float R0 = rdlane(v, 0), R1 = rdlane(v, 16), R2 = rdlane(v, 32), R3 = rdlane(v, 48);
  float T2 = R3, T1 = R2 + R3, T0 = R1 + T1;
  int row = lane >> 4;
  float T = (row == 0) ? T0 : ((row == 1) ? T1 : ((row == 2) ? T2 : 0.f));
  float ss0 = v + T;          // suffix sum of squares at dim 2*lane
  float total = R0 + T0;
  float ss1 = ss0 - a;        // suffix at dim 2*lane+1
  float c0 = x0 * __builtin_amdgcn_rsqf(ss0);
  float c1 = x1 * __builtin_amdgcn_rsqf(ss1);
  float rad = sqrtf(total);
  // unconditional common path, lane-63 override
  float2 sc0 = lutA[idx7c(c0)];
  float2 sc1 = lutA[idx7c(c1)];
  if (lane == 63) {
    int ib = 0;
    ib += c0 <  0.9009688679024191f;
    ib += c0 <  0.2225209339563144f;
    ib += c0 < -0.6234898018587336f;
    int i0 = (x1 < 0.f) ? (7 - ib) : ib;
    sc0 = lutB[i0];
    sc1 = make_float2(1.f, 1.f);   // dim 127 has no angle
  }
  // exclusive prefix product of sin over dims
  float qp = sc0.x * sc1.x;
  float w = qp;
  w *= dpp1<DPP_ROW_SHR(1)>(w);
  w *= dpp1<DPP_ROW_SHR(2)>(w);
  w *= dpp1<DPP_ROW_SHR(4)>(w);
  w *= dpp1<DPP_ROW_SHR(8)>(w);
  float e = dpp1<DPP_ROW_SHR(1)>(w);
  float F0 = rdlane(w, 15), F1 = rdlane(w, 31), F2 = rdlane(w, 47);
  float M1 = F0, M2 = F0 * F1, M3 = M2 * F2;
  float M = (row == 0) ? 1.f : ((row == 1) ? M1 : ((row == 2) ? M2 : M3));
  float E = e * M;            // prod of sin over dims < 2*lane
  float rE = rad * E;
  return make_float2(rE * sc0.y, rE * sc0.x * sc1.y);
}

__global__ __launch_bounds__(256, 4)
void attn_partial(const float* __restrict__ Q, const float* __restrict__ K,
                  const float* __restrict__ V, const float* __restrict__ noise,
                  float* __restrict__ part) {
  __shared__ __align__(16) char RAW[LDS_BYTES];
  unsigned short* Qs  = (unsigned short*)(RAW + OFF_QS);
  float*          Ps  = (float*)(RAW + OFF_PS);
  float2*         lutA = (float2*)(RAW + OFF_LUT);
  float2*         lutB = lutA + 8;
  float2*         Ml  = (float2*)(RAW + OFF_ML);   // [wave][q]
  unsigned short* Ks  = (unsigned short*)(RAW + OFF_KS);

  const int tid  = threadIdx.x;
  const int lane = tid & 63;
  const int wv   = tid >> 6;
  const int h    = blockIdx.x / BPH;
  const int bh   = blockIdx.x % BPH;

  if (tid < 8) {
    float fi = (float)tid / 7.0f;
    float ta = fi * 3.14159274101257324f;
    float tb = fi * 6.28318548202514648f;
    lutA[tid] = make_float2(sinf(ta), cosf(ta));
    lutB[tid] = make_float2(sinf(tb), cosf(tb));
  }
  {
    const float* Qh = Q + (size_t)h * NQ * DIM;
    for (int i = tid; i < NQ * DIM; i += 256)
      Qs[(i >> 7) * QPAD + (i & 127)] = f2bf(Qh[i] * QSCALE);
  }
  __syncthreads();

  const int G = lane >> 4, r16 = lane & 15;
  bf16x8 qa[4];
#pragma unroll
  for (int c = 0; c < 4; ++c)
    qa[c] = *(const bf16x8*)&Qs[r16 * QPAD + c * 32 + G * 8];

  f32x2 acc[NQ];
#pragma unroll
  for (int qq = 0; qq < NQ; ++qq) acc[qq] = (f32x2){0.f, 0.f};
  float m_r[4] = {-INFINITY, -INFINITY, -INFINITY, -INFINITY};
  float l_r[4] = {0.f, 0.f, 0.f, 0.f};

  const size_t hoff = (size_t)h * SEQT * DIM;
  const int t0 = bh * BTOK + wv * WTOK;
  const float2* Kp = (const float2*)(K + hoff + (size_t)t0 * DIM) + lane;
  const float2* Vp = (const float2*)(V + hoff + (size_t)t0 * DIM) + lane;
  const float* nh = noise + (size_t)h * NQ * SEQT + t0 + r16;
  unsigned short* myK = Ks + wv * TILE * QPAD;
  float* myP = Ps + wv * TILE * NQ;

#pragma unroll 1
  for (int tile = 0; tile < WTOK / TILE; ++tile) {
    // ---- decompress K tile -> LDS (bf16)
#pragma unroll 4
    for (int tt = 0; tt < TILE; ++tt) {
      float2 xv = Kp[(tile * TILE + tt) * 64];
      float2 kh = polar_rt(xv.x, xv.y, lane, lutA, lutB);
      unsigned pk = (unsigned)f2bf(kh.x) | ((unsigned)f2bf(kh.y) << 16);
      ((unsigned*)&myK[tt * QPAD])[lane] = pk;
    }
    // ---- scores via MFMA, K=128 chained
    f32x4 d0 = {0.f, 0.f, 0.f, 0.f};
#pragma unroll
    for (int c = 0; c < 4; ++c) {
      bf16x8 b0 = *(const bf16x8*)&myK[r16 * QPAD + c * 32 + G * 8];
      d0 = __builtin_amdgcn_mfma_f32_16x16x32_bf16(qa[c], b0, d0, 0, 0, 0);
    }
    const float* nt = nh + tile * TILE;
    float s0_[4];
#pragma unroll
    for (int rr = 0; rr < 4; ++rr)
      s0_[rr] = d0[rr] + nt[(size_t)(4 * G + rr) * SEQT];
    // ---- online softmax (quad G owns queries 4G..4G+3), DPP butterflies
    float al_r[4];
#pragma unroll
    for (int rr = 0; rr < 4; ++rr) {
      float mt = rmax16(s0_[rr]);
      float mn = fmaxf(m_r[rr], mt);
      al_r[rr] = __expf(m_r[rr] - mn);
      m_r[rr] = mn;
    }
    float p0[4];
#pragma unroll
    for (int rr = 0; rr < 4; ++rr) {
      p0[rr] = __expf(s0_[rr] - m_r[rr]);
      l_r[rr] = l_r[rr] * al_r[rr] + rsum16(p0[rr]);
    }
    *(float4*)&myP[r16 * NQ + 4 * G] = make_float4(p0[0], p0[1], p0[2], p0[3]);
#pragma unroll
    for (int qq = 0; qq < NQ; ++qq) {
      float alq = rdlane(al_r[qq & 3], (qq >> 2) << 4);
      acc[qq] *= (f32x2){alq, alq};    // v_pk_mul_f32
    }
    // ---- PV: decompress V straight into registers, packed fp32 FMA
#pragma unroll 2
    for (int tt = 0; tt < TILE; ++tt) {
      float2 xv = Vp[(tile * TILE + tt) * 64];
      float2 vh = polar_rt(xv.x, xv.y, lane, lutA, lutB);
      f32x2 vh2 = {vh.x, vh.y};
      const float* pv = &myP[tt * NQ];
      float4 pa = ((const float4*)pv)[0];
      float4 pb = ((const float4*)pv)[1];
      float4 pc = ((const float4*)pv)[2];
      float4 pd = ((const float4*)pv)[3];
      float pq[NQ] = {pa.x, pa.y, pa.z, pa.w, pb.x, pb.y, pb.z, pb.w,
                      pc.x, pc.y, pc.z, pc.w, pd.x, pd.y, pd.z, pd.w};
#pragma unroll
      for (int qq = 0; qq < NQ; ++qq)
        acc[qq] = __builtin_elementwise_fma((f32x2){pq[qq], pq[qq]}, vh2, acc[qq]);
    }
  }

  // ---- block-level merge of the 4 wave states (online-softmax combine)
  if (r16 == 0) {
#pragma unroll
    for (int rr = 0; rr < 4; ++rr)
      Ml[wv * NQ + 4 * G + rr] = make_float2(m_r[rr], l_r[rr]);
  }
  __syncthreads();   // also fences last Ks use before merge-buffer overlay
#pragma unroll
  for (int qq = 0; qq < NQ; ++qq) {
    float2 e0 = Ml[0 * NQ + qq], e1 = Ml[1 * NQ + qq];
    float2 e2 = Ml[2 * NQ + qq], e3 = Ml[3 * NQ + qq];
    float Mq = fmaxf(fmaxf(e0.x, e1.x), fmaxf(e2.x, e3.x));
    float own = (wv == 0) ? e0.x : ((wv == 1) ? e1.x : ((wv == 2) ? e2.x : e3.x));
    float al = __expf(own - Mq);
    acc[qq] *= (f32x2){al, al};
  }
  float* buf = (float*)(RAW + OFF_MERGE);
  if (wv >= 2) {
#pragma unroll
    for (int qq = 0; qq < NQ; ++qq)
      *(float2*)&buf[(wv - 2) * 2048 + qq * 128 + 2 * lane] =
          make_float2(acc[qq].x, acc[qq].y);
  }
  __syncthreads();
  if (wv < 2) {
#pragma unroll
    for (int qq = 0; qq < NQ; ++qq) {
      float2 t = *(const float2*)&buf[wv * 2048 + qq * 128 + 2 * lane];
      acc[qq] += (f32x2){t.x, t.y};
    }
  }
  __syncthreads();
  if (wv == 1) {
#pragma unroll
    for (int qq = 0; qq < NQ; ++qq)
      *(float2*)&buf[qq * 128 + 2 * lane] = make_float2(acc[qq].x, acc[qq].y);
  }
  __syncthreads();
  if (wv == 0) {
    float* P = part + ((size_t)h * NPART + bh) * (NQ * PSTR);
#pragma unroll
    for (int qq = 0; qq < NQ; ++qq) {
      float2 t = *(const float2*)&buf[qq * 128 + 2 * lane];
      *(float2*)&P[qq * PSTR + 4 + 2 * lane] =
          make_float2(acc[qq].x + t.x, acc[qq].y + t.y);
      // header (uniform across lanes; lane 0 stores)
      float2 e0 = Ml[0 * NQ + qq], e1 = Ml[1 * NQ + qq];
      float2 e2 = Ml[2 * NQ + qq], e3 = Ml[3 * NQ + qq];
      float Mq = fmaxf(fmaxf(e0.x, e1.x), fmaxf(e2.x, e3.x));
      float Lq = e0.y * __expf(e0.x - Mq) + e1.y * __expf(e1.x - Mq) +
                 e2.y * __expf(e2.x - Mq) + e3.y * __expf(e3.x - Mq);
      if (lane == 0) *(float2*)&P[qq * PSTR] = make_float2(Mq, Lq);
    }
  }
}

__global__ __launch_bounds__(128)
void attn_reduce(const float* __restrict__ part, float* __restrict__ out) {
  __shared__ float wgt[NPART];
  __shared__ float Lsh;
  const int tid = threadIdx.x;
  const int h = blockIdx.x >> 4;
  const int q = blockIdx.x & 15;
  const float* P = part + (size_t)h * NPART * NQ * PSTR;
  if (tid < NPART) {
    float2 ml = *(const float2*)&P[((size_t)tid * NQ + q) * PSTR];
    float M = ml.x;
#pragma unroll
    for (int off = 1; off < 64; off <<= 1)
      M = fmaxf(M, __shfl_xor(M, off, 64));
    float w = __expf(ml.x - M);
    wgt[tid] = w;
    float L = ml.y * w;
#pragma unroll
    for (int off = 1; off < 64; off <<= 1)
      L += __shfl_xor(L, off, 64);
    if (tid == 0) Lsh = L;
  }
  __syncthreads();
  const float* A = P + (size_t)q * PSTR + 4 + tid;
  float o = 0.f;
#pragma unroll 8
  for (int c = 0; c < NPART; ++c)
    o = fmaf(wgt[c], A[(size_t)c * NQ * PSTR], o);
  out[((size_t)h * NQ + q) * DIM + tid] = o * (1.0f / Lsh);
}

extern "C" void kernel_launch(void* const* d_in, const int* in_sizes, int n_in,
                              void* d_out, int out_size, void* d_ws, size_t ws_size,
                              hipStream_t stream) {
  (void)in_sizes; (void)n_in; (void)out_size; (void)ws_size;
  const float* Q = (const float*)d_in[0];
  const float* K = (const float*)d_in[1];
  const float* V = (const float*)d_in[2];
  const float* noise = (const float*)d_in[3];
  float* part = (float*)d_ws;  // 32*64*16*132*4 B = 17.3 MB
  attn_partial<<<dim3(HEADS * BPH), dim3(256), 0, stream>>>(Q, K, V, noise, part);
  attn_reduce<<<dim3(HEADS * NQ), dim3(128), 0, stream>>>(part, (float*)d_out);
}